// Round 5
// baseline (187.492 us; speedup 1.0000x reference)
//
#include <hip/hip_runtime.h>
#include <hip/hip_cooperative_groups.h>
#include <hip/hip_bf16.h>
#include <math.h>

namespace cg = cooperative_groups;

#define BATCH 16
#define NPTS 1024
#define DIM 64
#define EPSF 0.1f
#define INV_EPS 10.0f
#define MAX_ITER 100
#define THRESHF 0.1f
#define LSTRIDE 72  // shorts; 64+8 pad keeps b128 LDS reads conflict-cheap

typedef _Float16 h8 __attribute__((ext_vector_type(8)));
typedef short short8v __attribute__((ext_vector_type(8)));
typedef float float4v __attribute__((ext_vector_type(4)));

__device__ inline float waveSum(float x) {
#pragma unroll
  for (int off = 32; off; off >>= 1) x += __shfl_xor(x, off, 64);
  return x;
}
__device__ inline float waveMax(float x) {
#pragma unroll
  for (int off = 32; off; off >>= 1) x = fmaxf(x, __shfl_xor(x, off, 64));
  return x;
}

// One fused cooperative kernel. 256 blocks x 512 threads, 1 block/CU.
// Block owns rows [kslot*64, kslot*64+64) of batch (blk&7)+8*(blk>>7).
// K slab (64 rows x 1024 cols, fp16) lives ENTIRELY in registers:
// thread (wave,lane) holds rows wave*8+rr, cols [8*lane,+8) and [512+8*lane,+8).
__global__ __launch_bounds__(512, 2) void sinkhorn_fused(
    const float* __restrict__ x, const float* __restrict__ y,
    __hip_bfloat16* __restrict__ sxh, __hip_bfloat16* __restrict__ syh,
    float* __restrict__ x2, float* __restrict__ y2,
    float* __restrict__ partial,      // [2][BATCH][NPTS][16]
    float* __restrict__ deltaPub,     // [2][BATCH][16]
    float* __restrict__ errB,         // [MAX_ITER][BATCH], init -1
    unsigned* __restrict__ batchBar,  // [BATCH*64] padded
    unsigned* __restrict__ doneCnt, float* __restrict__ costAcc,
    float* __restrict__ out) {
  cg::grid_group grid = cg::this_grid();
  __shared__ short xs[64 * LSTRIDE];
  __shared__ short ys[2][64 * LSTRIDE];
  __shared__ short os[2][64 * LSTRIDE];
  __shared__ float wLDS[NPTS];
  __shared__ float vLDS[NPTS];
  __shared__ float colpart[8][NPTS];
  __shared__ float derr[8];
  __shared__ float errbL[BATCH];
  const int t = threadIdx.x;
  const int blk = blockIdx.x;
  const int wave = t >> 6, lane = t & 63;
  const int batch = (blk & 7) + 8 * (blk >> 7);  // 16 blocks/batch on one XCD
  const int kslot = (blk >> 3) & 15;
  const float log_mu = logf(1.0f / 1024.0f + 1e-8f);

  // ---- Phase 0: softmax of 128 rows (of 32768 total) + global init ----
  for (int i = wave; i < 128; i += 8) {
    int row = blk * 128 + i;
    const float* src;
    __hip_bfloat16* dst;
    float* ss;
    int r;
    if (row < BATCH * NPTS) {
      src = x; dst = sxh; ss = x2; r = row;
    } else {
      src = y; dst = syh; ss = y2; r = row - BATCH * NPTS;
    }
    float val = src[(size_t)r * DIM + lane];
    float m = waveMax(val);
    float e = expf(val - m);
    float s = waveSum(e);
    float p = e / s;
    dst[(size_t)r * DIM + lane] = (__hip_bfloat16)p;
    float sq = waveSum(p * p);
    if (lane == 0) ss[r] = sq;
  }
  if (blk == 0) {
    for (int i = t; i < MAX_ITER * BATCH; i += 512) errB[i] = -1.0f;
    if (t < BATCH) batchBar[t * 64] = 0u;
    if (t == 0) { doneCnt[0] = 0u; costAcc[0] = 0.f; }
  }
  grid.sync();

  // ---- Prologue: build this block's K slab into registers via MFMA ----
  const int m = lane & 15, q = lane >> 4;
  const int g = lane >> 3, sub = lane & 7;
  const int sw = wave & 3, ts = wave >> 2;
  {
    int r = t >> 3, c = t & 7;
    *(short8v*)&xs[r * LSTRIDE + c * 8] = *(const short8v*)(
        (const short*)sxh + ((size_t)batch * NPTS + kslot * 64 + r) * DIM + c * 8);
  }
  __syncthreads();
  short8v a0 = *(const short8v*)&xs[(sw * 16 + m) * LSTRIDE + q * 8];
  short8v a1 = *(const short8v*)&xs[(sw * 16 + m) * LSTRIDE + 32 + q * 8];
  float4 x4 = *(const float4*)(x2 + (size_t)batch * NPTS + kslot * 64 + sw * 16 + q * 4);
  float xa[4] = {x4.x, x4.y, x4.z, x4.w};
  h8 ka[8], kb[8];
#pragma unroll
  for (int k = 0; k < 8; k++) {
    // stage y rows [128k, 128k+128) of this batch -> ys[0], ys[1]
    {
      int idx = t;
#pragma unroll
      for (int rep = 0; rep < 2; rep++, idx += 512) {
        int r = idx >> 3, c = idx & 7;
        *(short8v*)&ys[r >> 6][(r & 63) * LSTRIDE + c * 8] = *(const short8v*)(
            (const short*)syh + ((size_t)batch * NPTS + 128 * k + r) * DIM + c * 8);
      }
    }
    __syncthreads();
    const int jt = 2 * k + ts;  // this wave's 64-col tile
    float4v accv[4];
#pragma unroll
    for (int tj = 0; tj < 4; tj++) {
      short8v b0 = *(const short8v*)&ys[ts][(tj * 16 + m) * LSTRIDE + q * 8];
      short8v b1 = *(const short8v*)&ys[ts][(tj * 16 + m) * LSTRIDE + 32 + q * 8];
      float4v c = {0.f, 0.f, 0.f, 0.f};
      c = __builtin_amdgcn_mfma_f32_16x16x32_bf16(a0, b0, c, 0, 0, 0);
      c = __builtin_amdgcn_mfma_f32_16x16x32_bf16(a1, b1, c, 0, 0, 0);
      accv[tj] = c;
    }
#pragma unroll
    for (int tj = 0; tj < 4; tj++) {
      float y2v = y2[(size_t)batch * NPTS + jt * 64 + tj * 16 + m];
#pragma unroll
      for (int reg = 0; reg < 4; reg++) {
        float C = xa[reg] + y2v - 2.0f * accv[tj][reg];
        _Float16 kv = (_Float16)expf(-INV_EPS * C);
        os[ts][(sw * 16 + q * 4 + reg) * LSTRIDE + tj * 16 + m] =
            *(const short*)&kv;
      }
    }
    __syncthreads();
    // consume: tiles 2k (os[0]) and 2k+1 (os[1]) feed lane groups g
    {
      int e0 = (2 * k) & 7, e1 = (2 * k + 1) & 7;
      if (g == e0 || g == e1) {
        const short* srcp = (g == e0) ? &os[0][0] : &os[1][0];
#pragma unroll
        for (int rr = 0; rr < 8; rr++) {
          h8 v = *(const h8*)&srcp[(wave * 8 + rr) * LSTRIDE + sub * 8];
          if (k < 4) ka[rr] = v; else kb[rr] = v;
        }
      }
    }
    __syncthreads();
  }

  for (int j = t; j < NPTS; j += 512) { vLDS[j] = 0.f; wLDS[j] = 1.f; }
  __syncthreads();

  float u[8];
#pragma unroll
  for (int r = 0; r < 8; r++) u[r] = 0.f;
  unsigned gen = 1;
  int it = 0;

  while (true) {
    // ---- Phase A: u update + column partials (K from registers) ----
    const float4* w4 = (const float4*)wLDS;
    float wreg[16];
    *(float4*)&wreg[0]  = w4[2 * lane];
    *(float4*)&wreg[4]  = w4[2 * lane + 1];
    *(float4*)&wreg[8]  = w4[128 + 2 * lane];
    *(float4*)&wreg[12] = w4[128 + 2 * lane + 1];
    float colreg[16];
#pragma unroll
    for (int n = 0; n < 16; n++) colreg[n] = 0.f;
    float delta = 0.f;
#pragma unroll
    for (int rr = 0; rr < 8; rr++) {
      float kf[16];
#pragma unroll
      for (int n = 0; n < 8; n++) {
        kf[n] = (float)ka[rr][n];
        kf[8 + n] = (float)kb[rr][n];
      }
      float dot = 0.f;
#pragma unroll
      for (int n = 0; n < 16; n++) dot = fmaf(kf[n], wreg[n], dot);
      dot = waveSum(dot);
      float uo = u[rr];
      float s = expf(INV_EPS * uo) * dot;
      float un = EPSF * (log_mu - logf(s + 1e-6f)) + uo;
      delta += fabsf(un - uo);
      u[rr] = un;
      float ai = expf(INV_EPS * un);
#pragma unroll
      for (int n = 0; n < 16; n++) colreg[n] = fmaf(kf[n], ai, colreg[n]);
    }
    if (lane == 0) derr[wave] = delta;
    {
      float4* cp = (float4*)&colpart[wave][0];
      cp[2 * lane]       = make_float4(colreg[0], colreg[1], colreg[2], colreg[3]);
      cp[2 * lane + 1]   = make_float4(colreg[4], colreg[5], colreg[6], colreg[7]);
      cp[128 + 2 * lane] = make_float4(colreg[8], colreg[9], colreg[10], colreg[11]);
      cp[128 + 2 * lane + 1] = make_float4(colreg[12], colreg[13], colreg[14], colreg[15]);
    }
    __syncthreads();
    float* pp = partial + ((size_t)(it & 1) * BATCH + batch) * NPTS * 16;
    for (int j = t; j < NPTS; j += 512) {
      float s = 0.f;
#pragma unroll
      for (int w = 0; w < 8; w++) s += colpart[w][j];
      pp[(size_t)j * 16 + kslot] = s;
    }
    if (t == 0) {
      float e = 0.f;
#pragma unroll
      for (int w = 0; w < 8; w++) e += derr[w];
      deltaPub[((it & 1) * BATCH + batch) * 16 + kslot] = e;
    }
    __syncthreads();
    // ---- per-batch barrier (16 blocks, same XCD) ----
    if (t == 0) {
      __hip_atomic_fetch_add(&batchBar[batch * 64], 1u, __ATOMIC_ACQ_REL,
                             __HIP_MEMORY_SCOPE_AGENT);
      while (__hip_atomic_load(&batchBar[batch * 64], __ATOMIC_ACQUIRE,
                               __HIP_MEMORY_SCOPE_AGENT) < 16u * gen)
        __builtin_amdgcn_s_sleep(1);
    }
    __syncthreads();
    gen++;
    if (kslot == 0 && t == 0) {
      const float* dp = deltaPub + ((it & 1) * BATCH + batch) * 16;
      float e = 0.f;
#pragma unroll
      for (int k = 0; k < 16; k++) e += dp[k];
      __hip_atomic_store(&errB[it * BATCH + batch], e, __ATOMIC_RELEASE,
                         __HIP_MEMORY_SCOPE_AGENT);
    }
    // ---- Phase B: v update (redundant per block, identical) ----
    for (int j = t; j < NPTS; j += 512) {
      const float4* pb = (const float4*)(pp + (size_t)j * 16);
      float4 p0 = pb[0], p1 = pb[1], p2 = pb[2], p3 = pb[3];
      float cs = p0.x + p0.y + p0.z + p0.w + p1.x + p1.y + p1.z + p1.w +
                 p2.x + p2.y + p2.z + p2.w + p3.x + p3.y + p3.z + p3.w;
      float vo = vLDS[j];
      float s = expf(INV_EPS * vo) * cs;
      float vn = EPSF * (log_mu - logf(s + 1e-6f)) + vo;
      vLDS[j] = vn;
      wLDS[j] = expf(INV_EPS * vn);
    }
    int itn = it + 1;
    if (itn >= MAX_ITER) { __syncthreads(); break; }
    // ---- cross-batch stop decision ----
    if (t < BATCH) {
      float v;
      while ((v = __hip_atomic_load(&errB[it * BATCH + t], __ATOMIC_ACQUIRE,
                                    __HIP_MEMORY_SCOPE_AGENT)) < 0.f)
        __builtin_amdgcn_s_sleep(1);
      errbL[t] = v;
    }
    __syncthreads();
    float errv = 0.f;
#pragma unroll
    for (int k = 0; k < BATCH; k++) errv += errbL[k];
    errv *= (1.0f / (float)BATCH);
    it = itn;
    if (errv < THRESHF) break;
  }

  // ---- Final cost: pi = a_i*K*w_j, C = -eps*log(K), K from registers ----
  {
    const float4* w4 = (const float4*)wLDS;
    float wreg[16];
    *(float4*)&wreg[0]  = w4[2 * lane];
    *(float4*)&wreg[4]  = w4[2 * lane + 1];
    *(float4*)&wreg[8]  = w4[128 + 2 * lane];
    *(float4*)&wreg[12] = w4[128 + 2 * lane + 1];
    float csum = 0.f;
#pragma unroll
    for (int rr = 0; rr < 8; rr++) {
      float kf[16];
#pragma unroll
      for (int n = 0; n < 8; n++) {
        kf[n] = (float)ka[rr][n];
        kf[8 + n] = (float)kb[rr][n];
      }
      float ai = expf(INV_EPS * u[rr]);
#pragma unroll
      for (int n = 0; n < 16; n++) {
        if (kf[n] > 0.f)
          csum += ai * wreg[n] * kf[n] * (-EPSF * logf(kf[n]));
      }
    }
    csum = waveSum(csum);
    if (lane == 0) derr[wave] = csum;
    __syncthreads();
    if (t == 0) {
      float cs = 0.f;
#pragma unroll
      for (int w = 0; w < 8; w++) cs += derr[w];
      atomicAdd(costAcc, cs);
      unsigned old = __hip_atomic_fetch_add(doneCnt, 1u, __ATOMIC_ACQ_REL,
                                            __HIP_MEMORY_SCOPE_AGENT);
      if (old == 255u) {
        float total = __hip_atomic_load(costAcc, __ATOMIC_ACQUIRE,
                                        __HIP_MEMORY_SCOPE_AGENT);
        out[0] = total * (1.0f / (float)BATCH);
      }
    }
  }
}

extern "C" void kernel_launch(void* const* d_in, const int* in_sizes, int n_in,
                              void* d_out, int out_size, void* d_ws,
                              size_t ws_size, hipStream_t stream) {
  (void)in_sizes; (void)n_in; (void)out_size; (void)ws_size;
  const float* x = (const float*)d_in[0];
  const float* y = (const float*)d_in[1];
  float* out = (float*)d_out;

  char* ws = (char*)d_ws;
  size_t off = 0;
  auto alloc = [&](size_t nbytes) -> void* {
    void* p = (void*)(ws + off);
    off = (off + nbytes + 255) & ~(size_t)255;
    return p;
  };
  __hip_bfloat16* sxh = (__hip_bfloat16*)alloc((size_t)BATCH * NPTS * DIM * 2);
  __hip_bfloat16* syh = (__hip_bfloat16*)alloc((size_t)BATCH * NPTS * DIM * 2);
  float* x2 = (float*)alloc((size_t)BATCH * NPTS * 4);
  float* y2 = (float*)alloc((size_t)BATCH * NPTS * 4);
  float* partial = (float*)alloc((size_t)2 * BATCH * NPTS * 16 * 4);
  float* deltaPub = (float*)alloc((size_t)2 * BATCH * 16 * 4);
  float* errB = (float*)alloc((size_t)MAX_ITER * BATCH * 4);
  unsigned* batchBar = (unsigned*)alloc((size_t)BATCH * 64 * 4);
  unsigned* doneCnt = (unsigned*)alloc(64);
  float* costAcc = (float*)alloc(64);

  void* args[] = {&x, &y, &sxh, &syh, &x2, &y2, &partial, &deltaPub,
                  &errB, &batchBar, &doneCnt, &costAcc, &out};
  hipLaunchCooperativeKernel((void*)sinkhorn_fused, dim3(256), dim3(512), args,
                             0, stream);
}